// Round 9
// baseline (344.126 us; speedup 1.0000x reference)
//
#include <hip/hip_runtime.h>
#include <hip/hip_bf16.h>

typedef float f32x4 __attribute__((ext_vector_type(4)));
typedef __bf16 bf16x8 __attribute__((ext_vector_type(8)));

// ---------------------------------------------------------------------------
// async global -> LDS, 16B/lane. LDS dest must be linear (wave base + lane*16).
// ---------------------------------------------------------------------------
__device__ __forceinline__ void gload16(const __bf16* g, __bf16* l) {
    __builtin_amdgcn_global_load_lds(
        (const __attribute__((address_space(1))) void*)g,
        (__attribute__((address_space(3))) void*)l, 16, 0, 0);
}

// Inline-asm LDS read: keeps the read OUT of the compiler's memory model so
// hipcc cannot attach conservative vmcnt(0) alias-drains vs global_load_lds
// destinations. Waits are done manually (lgkmcnt(0) + sched_barrier per phase).
__device__ __forceinline__ bf16x8 ldsr128(const __bf16* p) {
    bf16x8 r;
    asm volatile("ds_read_b128 %0, %1"
                 : "=v"(r)
                 : "v"((const __attribute__((address_space(3))) __bf16*)p));
    return r;
}

// Swizzled LDS fragment read (verified round5: SQ_LDS_BANK_CONFLICT == 0).
__device__ __forceinline__ bf16x8 frag(const __bf16* buf, int row, int kb) {
    int P = (row << 7) + (kb ^ ((row & 7) << 4));
    return ldsr128((const __bf16*)((const char*)buf + P));
}

// stage one 8KB chunk (64 rows x 64 cols bf16): linear LDS dest; global SOURCE
// is inverse-swizzled (same involution) so swizzled ds_reads see logical data.
#define STG(SRC, C, T, NTT, KK, DSTB)                                         \
    if ((T) < (NTT))                                                          \
        gload16((SRC) + (size_t)(C) * 64 * (KK) + (size_t)(T) * 64,           \
                (DSTB) + (C) * 4096 + t5 * 8)

#define LDA4(BUF, MO)                                                         \
    _Pragma("unroll") for (int m_ = 0; m_ < 4; ++m_) {                        \
        a[m_][0] = frag(BUF, wr * 128 + (m_ + MO) * 16 + fr, kq * 16);        \
        a[m_][1] = frag(BUF, wr * 128 + (m_ + MO) * 16 + fr, 64 + kq * 16);   \
    }

#define LDB2(DST, BUF)                                                        \
    _Pragma("unroll") for (int n_ = 0; n_ < 2; ++n_) {                        \
        DST[n_][0] = frag(BUF, wc * 32 + n_ * 16 + fr, kq * 16);              \
        DST[n_][1] = frag(BUF, wc * 32 + n_ * 16 + fr, 64 + kq * 16);         \
    }

// wait discipline: barrier, then explicit lgkmcnt(0), then a full
// sched_barrier so no MFMA is hoisted above the wait (rule 18), then MFMA.
#define MFMA16(ACC, BF, MO)                                                   \
    asm volatile("s_waitcnt lgkmcnt(0)" ::: "memory");                        \
    __builtin_amdgcn_sched_barrier(0);                                        \
    __builtin_amdgcn_s_setprio(1);                                            \
    _Pragma("unroll") for (int m_ = 0; m_ < 4; ++m_) {                        \
        _Pragma("unroll") for (int n_ = 0; n_ < 2; ++n_) {                    \
            ACC[m_ + MO][n_] = __builtin_amdgcn_mfma_f32_16x16x32_bf16(       \
                a[m_][0], BF[n_][0], ACC[m_ + MO][n_], 0, 0, 0);              \
            ACC[m_ + MO][n_] = __builtin_amdgcn_mfma_f32_16x16x32_bf16(       \
                a[m_][1], BF[n_][1], ACC[m_ + MO][n_], 0, 0, 0);              \
        }                                                                     \
    }                                                                         \
    __builtin_amdgcn_s_setprio(0);

#define BAR() __builtin_amdgcn_s_barrier()
#define WAITV(N) asm volatile("s_waitcnt vmcnt(" #N ")" ::: "memory")
#define WAITL(N) asm volatile("s_waitcnt lgkmcnt(" #N ")" ::: "memory")
#define SCHB()   __builtin_amdgcn_sched_barrier(0)

// ---------------------------------------------------------------------------
// fp32 -> bf16 conversion, 8 elems/thread/iter
// ---------------------------------------------------------------------------
__global__ __launch_bounds__(256) void cvt_bf16(const float* __restrict__ src,
                                                __bf16* __restrict__ dst,
                                                int n8) {
    int i = blockIdx.x * blockDim.x + threadIdx.x;
    int stride = gridDim.x * blockDim.x;
    const f32x4* s4 = (const f32x4*)src;
    bf16x8* d8 = (bf16x8*)dst;
    for (; i < n8; i += stride) {
        f32x4 va = s4[2 * i];
        f32x4 vb = s4[2 * i + 1];
        bf16x8 o;
        o[0] = (__bf16)va[0]; o[1] = (__bf16)va[1];
        o[2] = (__bf16)va[2]; o[3] = (__bf16)va[3];
        o[4] = (__bf16)vb[0]; o[5] = (__bf16)vb[1];
        o[6] = (__bf16)vb[2]; o[7] = (__bf16)vb[3];
        d8[i] = o;
    }
}

// ---------------------------------------------------------------------------
// Gate+Up GEMM — EXACT round-6 verified kernel (140.9us, MfmaUtil 43, pass).
// 8-phase schedule. M=8192, N=4096, K=1024. BM=256, BN=128, BK=64.
// ---------------------------------------------------------------------------
__global__ __launch_bounds__(512, 2) void ffn_gateup(
    const __bf16* __restrict__ X,   // [8192,1024]
    const __bf16* __restrict__ Wg,  // [4096,1024]
    const __bf16* __restrict__ Wu,  // [4096,1024]
    __bf16* __restrict__ Hm)        // [8192,4096]
{
    constexpr int K = 1024, NT = 16;
    __shared__ __bf16 lds[65536];          // 128 KiB
    __bf16* const A0p = lds;
    __bf16* const A1p = lds + 16384;
    __bf16* const G0p = lds + 32768;
    __bf16* const G1p = lds + 40960;
    __bf16* const U0p = lds + 49152;
    __bf16* const U1p = lds + 57344;

    const int t5 = threadIdx.x;
    const int lane = t5 & 63, w = t5 >> 6;
    const int wr = w >> 2, wc = w & 3;
    const int fr = lane & 15, kq = lane >> 4;

    const int brow = blockIdx.y * 256;
    const int bcol = blockIdx.x * 128;

    const int srow = t5 >> 3;
    const int scol = (((t5 & 7) ^ ((t5 >> 3) & 7)) << 3);   // inverse swizzle

    const __bf16* Xs = X  + (size_t)(brow + srow) * K + scol;
    const __bf16* Gg = Wg + (size_t)(bcol + srow) * K + scol;
    const __bf16* Uu = Wu + (size_t)(bcol + srow) * K + scol;

    f32x4 accg[8][2] = {}, accu[8][2] = {};
    bf16x8 a[4][2], g[2][2], u[2][2];

    // prologue: tile0 full (8 loads), tile1 A02+G+U (6 loads)
    STG(Xs, 0, 0, NT, K, A0p); STG(Xs, 2, 0, NT, K, A0p);
    STG(Gg, 0, 0, NT, K, G0p); STG(Gg, 1, 0, NT, K, G0p);
    STG(Uu, 0, 0, NT, K, U0p); STG(Uu, 1, 0, NT, K, U0p);
    STG(Xs, 1, 0, NT, K, A0p); STG(Xs, 3, 0, NT, K, A0p);
    STG(Xs, 0, 1, NT, K, A1p); STG(Xs, 2, 1, NT, K, A1p);
    STG(Gg, 0, 1, NT, K, G1p); STG(Gg, 1, 1, NT, K, G1p);
    STG(Uu, 0, 1, NT, K, U1p); STG(Uu, 1, 1, NT, K, U1p);
    WAITV(6);
    BAR();

    for (int t = 0; t < NT; t += 2) {
        // ---- p0: tile t, gate, mh0 ----
        LDA4(A0p, 0);
        LDB2(g, G0p);
        STG(Xs, 1, t + 1, NT, K, A1p); STG(Xs, 3, t + 1, NT, K, A1p);
        BAR();
        MFMA16(accg, g, 0);
        BAR();
        // ---- p1: tile t, up, mh0 ----
        LDB2(u, U0p);
        STG(Xs, 0, t + 2, NT, K, A0p); STG(Xs, 2, t + 2, NT, K, A0p);
        BAR();
        MFMA16(accu, u, 0);
        BAR();
        // ---- p2: tile t, gate, mh1 ----
        LDA4(A0p, 4);
        STG(Gg, 0, t + 2, NT, K, G0p); STG(Gg, 1, t + 2, NT, K, G0p);
        BAR();
        MFMA16(accg, g, 4);
        BAR();
        // ---- p3: tile t, up, mh1 ----
        STG(Uu, 0, t + 2, NT, K, U0p); STG(Uu, 1, t + 2, NT, K, U0p);
        BAR();
        MFMA16(accu, u, 4);
        if (t + 2 < NT) { WAITV(6); } else { WAITV(0); }
        BAR();
        // ---- p4: tile t+1, gate, mh0 ----
        LDA4(A1p, 0);
        LDB2(g, G1p);
        STG(Xs, 1, t + 2, NT, K, A0p); STG(Xs, 3, t + 2, NT, K, A0p);
        BAR();
        MFMA16(accg, g, 0);
        BAR();
        // ---- p5: tile t+1, up, mh0 ----
        LDB2(u, U1p);
        STG(Xs, 0, t + 3, NT, K, A1p); STG(Xs, 2, t + 3, NT, K, A1p);
        BAR();
        MFMA16(accu, u, 0);
        BAR();
        // ---- p6: tile t+1, gate, mh1 ----
        LDA4(A1p, 4);
        STG(Gg, 0, t + 3, NT, K, G1p); STG(Gg, 1, t + 3, NT, K, G1p);
        BAR();
        MFMA16(accg, g, 4);
        BAR();
        // ---- p7: tile t+1, up, mh1 ----
        STG(Uu, 0, t + 3, NT, K, U1p); STG(Uu, 1, t + 3, NT, K, U1p);
        BAR();
        MFMA16(accu, u, 4);
        if (t + 3 < NT) { WAITV(6); } else { WAITV(0); }
        BAR();
    }

    // epilogue: C/D layout col = lane&15, row = (lane>>4)*4 + j
    #pragma unroll
    for (int m = 0; m < 8; ++m) {
        #pragma unroll
        for (int n = 0; n < 2; ++n) {
            const int row0 = brow + wr * 128 + m * 16 + kq * 4;
            const int col  = bcol + wc * 32 + n * 16 + fr;
            #pragma unroll
            for (int j = 0; j < 4; ++j) {
                float gg = accg[m][n][j];
                float uu = accu[m][n][j];
                float h = (gg / (1.0f + __expf(-gg))) * uu;
                Hm[(size_t)(row0 + j) * 4096 + col] = (__bf16)h;
            }
        }
    }
}

// ---------------------------------------------------------------------------
// Down GEMM, NEW geometry: BM=128, BN=128 -> grid 8x64 = 512 blocks
// = 2 blocks/CU (4 waves/SIMD) for latency hiding. 512 threads, 8 waves
// (2M x 4N), wave tile 64x32. LDS 64KB: A/B double-buffered 16KB each.
// Per K-tile: read all 12 frags at p0 (WAITL(0)+SCHB, verified-safe pattern);
// stage t+2 into the just-read buffer at p1 (reads globally complete via
// p0's WAITL(0)+BAR). Counted WAITV(4) at tile end (drains prev tile's 4
// stages = next tile's data), never 0 in steady state.
// ---------------------------------------------------------------------------
#define DLDA4(BUF)                                                            \
    _Pragma("unroll") for (int m_ = 0; m_ < 4; ++m_) {                        \
        a[m_][0] = frag(BUF, wr * 64 + m_ * 16 + fr, kq * 16);                \
        a[m_][1] = frag(BUF, wr * 64 + m_ * 16 + fr, 64 + kq * 16);           \
    }

#define DMFMA8(MO)                                                            \
    __builtin_amdgcn_s_setprio(1);                                            \
    _Pragma("unroll") for (int m_ = 0; m_ < 2; ++m_) {                        \
        _Pragma("unroll") for (int n_ = 0; n_ < 2; ++n_) {                    \
            acc[m_ + MO][n_] = __builtin_amdgcn_mfma_f32_16x16x32_bf16(       \
                a[m_ + MO][0], b[n_][0], acc[m_ + MO][n_], 0, 0, 0);          \
            acc[m_ + MO][n_] = __builtin_amdgcn_mfma_f32_16x16x32_bf16(       \
                a[m_ + MO][1], b[n_][1], acc[m_ + MO][n_], 0, 0, 0);          \
        }                                                                     \
    }                                                                         \
    __builtin_amdgcn_s_setprio(0);

#define DN_TILE(CA, CB, T)                                                    \
    DLDA4(CA);                                                                \
    LDB2(b, CB);                                                              \
    WAITL(0); SCHB();                                                         \
    DMFMA8(0);                                                                \
    BAR();                                                                    \
    STG(Hs, 0, (T) + 2, NT, K, CA); STG(Hs, 1, (T) + 2, NT, K, CA);           \
    STG(Ws, 0, (T) + 2, NT, K, CB); STG(Ws, 1, (T) + 2, NT, K, CB);           \
    DMFMA8(2);                                                                \
    if ((T) + 2 < NT) { WAITV(4); } else { WAITV(0); }                        \
    BAR();

__global__ __launch_bounds__(512, 4) void ffn_down(
    const __bf16* __restrict__ Hm,  // [8192,4096]
    const __bf16* __restrict__ Wd,  // [1024,4096]
    float* __restrict__ Y)          // [8192,1024]
{
    constexpr int K = 4096, NT = 64;
    __shared__ __bf16 lds[32768];          // 64 KiB
    __bf16* const A0p = lds;               // 16KB: [128][64] bf16
    __bf16* const A1p = lds + 8192;
    __bf16* const B0p = lds + 16384;
    __bf16* const B1p = lds + 24576;

    const int t5 = threadIdx.x;
    const int lane = t5 & 63, w = t5 >> 6;
    const int wr = w >> 2, wc = w & 3;     // 2M x 4N
    const int fr = lane & 15, kq = lane >> 4;

    const int brow = blockIdx.y * 128;
    const int bcol = blockIdx.x * 128;

    const int srow = t5 >> 3;
    const int scol = (((t5 & 7) ^ ((t5 >> 3) & 7)) << 3);

    const __bf16* Hs = Hm + (size_t)(brow + srow) * K + scol;
    const __bf16* Ws = Wd + (size_t)(bcol + srow) * K + scol;

    f32x4 acc[4][2] = {};
    bf16x8 a[4][2], b[2][2];

    // prologue: tile0 (4 chunks) then tile1 (4 chunks); force tile0 complete.
    STG(Hs, 0, 0, NT, K, A0p); STG(Hs, 1, 0, NT, K, A0p);
    STG(Ws, 0, 0, NT, K, B0p); STG(Ws, 1, 0, NT, K, B0p);
    STG(Hs, 0, 1, NT, K, A1p); STG(Hs, 1, 1, NT, K, A1p);
    STG(Ws, 0, 1, NT, K, B1p); STG(Ws, 1, 1, NT, K, B1p);
    WAITV(4);
    BAR();

    for (int t = 0; t < NT; t += 2) {
        DN_TILE(A0p, B0p, t)
        DN_TILE(A1p, B1p, t + 1)
    }
    WAITL(0); WAITV(0);

    #pragma unroll
    for (int m = 0; m < 4; ++m) {
        #pragma unroll
        for (int n = 0; n < 2; ++n) {
            const int row0 = brow + wr * 64 + m * 16 + kq * 4;
            const int col  = bcol + wc * 32 + n * 16 + fr;
            #pragma unroll
            for (int j = 0; j < 4; ++j) {
                Y[(size_t)(row0 + j) * 1024 + col] = acc[m][n][j];
            }
        }
    }
}

// ---------------------------------------------------------------------------
extern "C" void kernel_launch(void* const* d_in, const int* in_sizes, int n_in,
                              void* d_out, int out_size, void* d_ws, size_t ws_size,
                              hipStream_t stream) {
    const float* x  = (const float*)d_in[0];
    const float* wg = (const float*)d_in[1];
    const float* wu = (const float*)d_in[2];
    const float* wd = (const float*)d_in[3];
    float* y = (float*)d_out;

    const size_t M = 8192, H = 1024, I = 4096;

    __bf16* Xb  = (__bf16*)d_ws;
    __bf16* Wgb = Xb + M * H;
    __bf16* Wub = Wgb + I * H;
    __bf16* Wdb = Wub + I * H;
    __bf16* Hm  = Wdb + H * I;
    // needed: (M*H + 3*I*H + M*I)*2 bytes = 104 MiB

    cvt_bf16<<<1024, 256, 0, stream>>>(x,  Xb,  (int)(M * H / 8));
    cvt_bf16<<<512,  256, 0, stream>>>(wg, Wgb, (int)(I * H / 8));
    cvt_bf16<<<512,  256, 0, stream>>>(wu, Wub, (int)(I * H / 8));
    cvt_bf16<<<512,  256, 0, stream>>>(wd, Wdb, (int)(H * I / 8));

    ffn_gateup<<<dim3(I / 128, M / 256), 512, 0, stream>>>(Xb, Wgb, Wub, Hm);
    ffn_down  <<<dim3(H / 128, M / 128), 512, 0, stream>>>(Hm, Wdb, y);
}

// Round 10
// 323.018 us; speedup vs baseline: 1.0653x; 1.0653x over previous
//
#include <hip/hip_runtime.h>
#include <hip/hip_bf16.h>

typedef float f32x4 __attribute__((ext_vector_type(4)));
typedef __bf16 bf16x8 __attribute__((ext_vector_type(8)));

// ---------------------------------------------------------------------------
// async global -> LDS, 16B/lane. LDS dest must be linear (wave base + lane*16).
// ---------------------------------------------------------------------------
__device__ __forceinline__ void gload16(const __bf16* g, __bf16* l) {
    __builtin_amdgcn_global_load_lds(
        (const __attribute__((address_space(1))) void*)g,
        (__attribute__((address_space(3))) void*)l, 16, 0, 0);
}

// Inline-asm LDS read: keeps the read OUT of the compiler's memory model so
// hipcc cannot attach conservative vmcnt(0) alias-drains vs global_load_lds
// destinations. Waits are done manually (lgkmcnt + sched_barrier per phase).
__device__ __forceinline__ bf16x8 ldsr128(const __bf16* p) {
    bf16x8 r;
    asm volatile("ds_read_b128 %0, %1"
                 : "=v"(r)
                 : "v"((const __attribute__((address_space(3))) __bf16*)p));
    return r;
}

// Swizzled LDS fragment read (verified round5: SQ_LDS_BANK_CONFLICT == 0).
__device__ __forceinline__ bf16x8 frag(const __bf16* buf, int row, int kb) {
    int P = (row << 7) + (kb ^ ((row & 7) << 4));
    return ldsr128((const __bf16*)((const char*)buf + P));
}

// stage one 8KB chunk (64 rows x 64 cols bf16): linear LDS dest; global SOURCE
// is inverse-swizzled (same involution) so swizzled ds_reads see logical data.
#define STG(SRC, C, T, NTT, KK, DSTB)                                         \
    if ((T) < (NTT))                                                          \
        gload16((SRC) + (size_t)(C) * 64 * (KK) + (size_t)(T) * 64,           \
                (DSTB) + (C) * 4096 + t5 * 8)

#define LDA4(BUF, MO)                                                         \
    _Pragma("unroll") for (int m_ = 0; m_ < 4; ++m_) {                        \
        a[m_][0] = frag(BUF, wr * 128 + (m_ + MO) * 16 + fr, kq * 16);        \
        a[m_][1] = frag(BUF, wr * 128 + (m_ + MO) * 16 + fr, 64 + kq * 16);   \
    }

#define LDB2(DST, BUF)                                                        \
    _Pragma("unroll") for (int n_ = 0; n_ < 2; ++n_) {                        \
        DST[n_][0] = frag(BUF, wc * 32 + n_ * 16 + fr, kq * 16);              \
        DST[n_][1] = frag(BUF, wc * 32 + n_ * 16 + fr, 64 + kq * 16);         \
    }

// wait discipline: barrier, then explicit lgkmcnt(0), then a full
// sched_barrier so no MFMA is hoisted above the wait (rule 18), then MFMA.
#define MFMA16(ACC, BF, MO)                                                   \
    asm volatile("s_waitcnt lgkmcnt(0)" ::: "memory");                        \
    __builtin_amdgcn_sched_barrier(0);                                        \
    __builtin_amdgcn_s_setprio(1);                                            \
    _Pragma("unroll") for (int m_ = 0; m_ < 4; ++m_) {                        \
        _Pragma("unroll") for (int n_ = 0; n_ < 2; ++n_) {                    \
            ACC[m_ + MO][n_] = __builtin_amdgcn_mfma_f32_16x16x32_bf16(       \
                a[m_][0], BF[n_][0], ACC[m_ + MO][n_], 0, 0, 0);              \
            ACC[m_ + MO][n_] = __builtin_amdgcn_mfma_f32_16x16x32_bf16(       \
                a[m_][1], BF[n_][1], ACC[m_ + MO][n_], 0, 0, 0);              \
        }                                                                     \
    }                                                                         \
    __builtin_amdgcn_s_setprio(0);

#define BAR() __builtin_amdgcn_s_barrier()
#define WAITV(N) asm volatile("s_waitcnt vmcnt(" #N ")" ::: "memory")
#define WAITL(N) asm volatile("s_waitcnt lgkmcnt(" #N ")" ::: "memory")
#define SCHB()   __builtin_amdgcn_sched_barrier(0)

// ---------------------------------------------------------------------------
// fused fp32 -> bf16 conversion for all four inputs (one launch)
// ---------------------------------------------------------------------------
__global__ __launch_bounds__(256) void cvt_all(
    const float* __restrict__ x,  const float* __restrict__ wg,
    const float* __restrict__ wu, const float* __restrict__ wd,
    __bf16* __restrict__ xb,  __bf16* __restrict__ wgb,
    __bf16* __restrict__ wub, __bf16* __restrict__ wdb) {
    // group counts (8 elems each): x 1048576, wg/wu/wd 524288 each
    int i = blockIdx.x * blockDim.x + threadIdx.x;
    int stride = gridDim.x * blockDim.x;
    for (; i < 2621440; i += stride) {
        const float* src; __bf16* dst; int off;
        if (i < 1048576)      { src = x;  dst = xb;  off = i; }
        else if (i < 1572864) { src = wg; dst = wgb; off = i - 1048576; }
        else if (i < 2097152) { src = wu; dst = wub; off = i - 1572864; }
        else                  { src = wd; dst = wdb; off = i - 2097152; }
        f32x4 va = ((const f32x4*)src)[2 * off];
        f32x4 vb = ((const f32x4*)src)[2 * off + 1];
        bf16x8 o;
        o[0] = (__bf16)va[0]; o[1] = (__bf16)va[1];
        o[2] = (__bf16)va[2]; o[3] = (__bf16)va[3];
        o[4] = (__bf16)vb[0]; o[5] = (__bf16)vb[1];
        o[6] = (__bf16)vb[2]; o[7] = (__bf16)vb[3];
        ((bf16x8*)dst)[off] = o;
    }
}

// ---------------------------------------------------------------------------
// Gate+Up GEMM — EXACT round-6 verified kernel (pass x2, ~143us, MfmaUtil 42).
// 8-phase schedule. M=8192, N=4096, K=1024. BM=256, BN=128, BK=64.
// ---------------------------------------------------------------------------
__global__ __launch_bounds__(512, 2) void ffn_gateup(
    const __bf16* __restrict__ X,   // [8192,1024]
    const __bf16* __restrict__ Wg,  // [4096,1024]
    const __bf16* __restrict__ Wu,  // [4096,1024]
    __bf16* __restrict__ Hm)        // [8192,4096]
{
    constexpr int K = 1024, NT = 16;
    __shared__ __bf16 lds[65536];          // 128 KiB
    __bf16* const A0p = lds;
    __bf16* const A1p = lds + 16384;
    __bf16* const G0p = lds + 32768;
    __bf16* const G1p = lds + 40960;
    __bf16* const U0p = lds + 49152;
    __bf16* const U1p = lds + 57344;

    const int t5 = threadIdx.x;
    const int lane = t5 & 63, w = t5 >> 6;
    const int wr = w >> 2, wc = w & 3;
    const int fr = lane & 15, kq = lane >> 4;

    const int brow = blockIdx.y * 256;
    const int bcol = blockIdx.x * 128;

    const int srow = t5 >> 3;
    const int scol = (((t5 & 7) ^ ((t5 >> 3) & 7)) << 3);   // inverse swizzle

    const __bf16* Xs = X  + (size_t)(brow + srow) * K + scol;
    const __bf16* Gg = Wg + (size_t)(bcol + srow) * K + scol;
    const __bf16* Uu = Wu + (size_t)(bcol + srow) * K + scol;

    f32x4 accg[8][2] = {}, accu[8][2] = {};
    bf16x8 a[4][2], g[2][2], u[2][2];

    // prologue: tile0 full (8 loads), tile1 A02+G+U (6 loads)
    STG(Xs, 0, 0, NT, K, A0p); STG(Xs, 2, 0, NT, K, A0p);
    STG(Gg, 0, 0, NT, K, G0p); STG(Gg, 1, 0, NT, K, G0p);
    STG(Uu, 0, 0, NT, K, U0p); STG(Uu, 1, 0, NT, K, U0p);
    STG(Xs, 1, 0, NT, K, A0p); STG(Xs, 3, 0, NT, K, A0p);
    STG(Xs, 0, 1, NT, K, A1p); STG(Xs, 2, 1, NT, K, A1p);
    STG(Gg, 0, 1, NT, K, G1p); STG(Gg, 1, 1, NT, K, G1p);
    STG(Uu, 0, 1, NT, K, U1p); STG(Uu, 1, 1, NT, K, U1p);
    WAITV(6);
    BAR();

    for (int t = 0; t < NT; t += 2) {
        // ---- p0: tile t, gate, mh0 ----
        LDA4(A0p, 0);
        LDB2(g, G0p);
        STG(Xs, 1, t + 1, NT, K, A1p); STG(Xs, 3, t + 1, NT, K, A1p);
        BAR();
        MFMA16(accg, g, 0);
        BAR();
        // ---- p1: tile t, up, mh0 ----
        LDB2(u, U0p);
        STG(Xs, 0, t + 2, NT, K, A0p); STG(Xs, 2, t + 2, NT, K, A0p);
        BAR();
        MFMA16(accu, u, 0);
        BAR();
        // ---- p2: tile t, gate, mh1 ----
        LDA4(A0p, 4);
        STG(Gg, 0, t + 2, NT, K, G0p); STG(Gg, 1, t + 2, NT, K, G0p);
        BAR();
        MFMA16(accg, g, 4);
        BAR();
        // ---- p3: tile t, up, mh1 ----
        STG(Uu, 0, t + 2, NT, K, U0p); STG(Uu, 1, t + 2, NT, K, U0p);
        BAR();
        MFMA16(accu, u, 4);
        if (t + 2 < NT) { WAITV(6); } else { WAITV(0); }
        BAR();
        // ---- p4: tile t+1, gate, mh0 ----
        LDA4(A1p, 0);
        LDB2(g, G1p);
        STG(Xs, 1, t + 2, NT, K, A0p); STG(Xs, 3, t + 2, NT, K, A0p);
        BAR();
        MFMA16(accg, g, 0);
        BAR();
        // ---- p5: tile t+1, up, mh0 ----
        LDB2(u, U1p);
        STG(Xs, 0, t + 3, NT, K, A1p); STG(Xs, 2, t + 3, NT, K, A1p);
        BAR();
        MFMA16(accu, u, 0);
        BAR();
        // ---- p6: tile t+1, gate, mh1 ----
        LDA4(A1p, 4);
        STG(Gg, 0, t + 3, NT, K, G1p); STG(Gg, 1, t + 3, NT, K, G1p);
        BAR();
        MFMA16(accg, g, 4);
        BAR();
        // ---- p7: tile t+1, up, mh1 ----
        STG(Uu, 0, t + 3, NT, K, U1p); STG(Uu, 1, t + 3, NT, K, U1p);
        BAR();
        MFMA16(accu, u, 4);
        if (t + 3 < NT) { WAITV(6); } else { WAITV(0); }
        BAR();
    }

    // epilogue: C/D layout col = lane&15, row = (lane>>4)*4 + j
    #pragma unroll
    for (int m = 0; m < 8; ++m) {
        #pragma unroll
        for (int n = 0; n < 2; ++n) {
            const int row0 = brow + wr * 128 + m * 16 + kq * 4;
            const int col  = bcol + wc * 32 + n * 16 + fr;
            #pragma unroll
            for (int j = 0; j < 4; ++j) {
                float gg = accg[m][n][j];
                float uu = accu[m][n][j];
                float h = (gg / (1.0f + __expf(-gg))) * uu;
                Hm[(size_t)(row0 + j) * 4096 + col] = (__bf16)h;
            }
        }
    }
}

// ---------------------------------------------------------------------------
// Down GEMM, wave-tile 64x64 geometry (FLOP/LDS-byte 32 vs old 21.3).
// M=8192, N=1024, K=4096. BM=256, BN=128, 512 thr, 8 waves as 4M x 2N.
// Grid 8x32 = 256 blocks = 1/CU (minimal cache traffic 768MB). LDS 96KB:
// A dbuf 2x32KB, B dbuf 2x16KB. Verified DN ledger: reads -> WAITL(0)+SCHB ->
// MFMA h1 -> BAR -> 6 STG(t+2) into just-read bufs -> MFMA h2 -> WAITV(6).
// launch_bounds (512,1): acc 64 + frags 64 VGPR; declaring 2 would spill.
// ---------------------------------------------------------------------------
#define DLDA(BUF)                                                             \
    _Pragma("unroll") for (int m_ = 0; m_ < 4; ++m_) {                        \
        a[m_][0] = frag(BUF, wr * 64 + m_ * 16 + fr, kq * 16);                \
        a[m_][1] = frag(BUF, wr * 64 + m_ * 16 + fr, 64 + kq * 16);           \
    }

#define DLDB(BUF)                                                             \
    _Pragma("unroll") for (int n_ = 0; n_ < 4; ++n_) {                        \
        b[n_][0] = frag(BUF, wc * 64 + n_ * 16 + fr, kq * 16);                \
        b[n_][1] = frag(BUF, wc * 64 + n_ * 16 + fr, 64 + kq * 16);           \
    }

#define DMFMA16(MO)                                                           \
    __builtin_amdgcn_s_setprio(1);                                            \
    _Pragma("unroll") for (int m_ = 0; m_ < 2; ++m_) {                        \
        _Pragma("unroll") for (int n_ = 0; n_ < 4; ++n_) {                    \
            acc[m_ + MO][n_] = __builtin_amdgcn_mfma_f32_16x16x32_bf16(       \
                a[m_ + MO][0], b[n_][0], acc[m_ + MO][n_], 0, 0, 0);          \
            acc[m_ + MO][n_] = __builtin_amdgcn_mfma_f32_16x16x32_bf16(       \
                a[m_ + MO][1], b[n_][1], acc[m_ + MO][n_], 0, 0, 0);          \
        }                                                                     \
    }                                                                         \
    __builtin_amdgcn_s_setprio(0);

#define DN_TILE(CA, CB, T)                                                    \
    DLDA(CA);                                                                 \
    DLDB(CB);                                                                 \
    WAITL(0); SCHB();                                                         \
    DMFMA16(0);                                                               \
    BAR();                                                                    \
    STG(Hs, 0, (T) + 2, NT, K, CA); STG(Hs, 1, (T) + 2, NT, K, CA);           \
    STG(Hs, 2, (T) + 2, NT, K, CA); STG(Hs, 3, (T) + 2, NT, K, CA);           \
    STG(Ws, 0, (T) + 2, NT, K, CB); STG(Ws, 1, (T) + 2, NT, K, CB);           \
    DMFMA16(2);                                                               \
    if ((T) + 2 < NT) { WAITV(6); } else { WAITV(0); }                        \
    BAR();

__global__ __launch_bounds__(512, 1) void ffn_down(
    const __bf16* __restrict__ Hm,  // [8192,4096]
    const __bf16* __restrict__ Wd,  // [1024,4096]
    float* __restrict__ Y)          // [8192,1024]
{
    constexpr int K = 4096, NT = 64;
    __shared__ __bf16 lds[49152];          // 96 KiB
    __bf16* const A0p = lds;               // 32KB: [256][64] bf16
    __bf16* const A1p = lds + 16384;
    __bf16* const B0p = lds + 32768;       // 16KB: [128][64] bf16
    __bf16* const B1p = lds + 40960;

    const int t5 = threadIdx.x;
    const int lane = t5 & 63, w = t5 >> 6;
    const int wr = w >> 1, wc = w & 1;     // 4M x 2N, wave tile 64x64
    const int fr = lane & 15, kq = lane >> 4;

    const int brow = blockIdx.y * 256;
    const int bcol = blockIdx.x * 128;

    const int srow = t5 >> 3;
    const int scol = (((t5 & 7) ^ ((t5 >> 3) & 7)) << 3);

    const __bf16* Hs = Hm + (size_t)(brow + srow) * K + scol;
    const __bf16* Ws = Wd + (size_t)(bcol + srow) * K + scol;

    f32x4 acc[4][4] = {};
    bf16x8 a[4][2], b[4][2];

    // prologue: tile0 (6 chunks) + tile1 (6 chunks); WAITV(6) -> tile0 done.
    STG(Hs, 0, 0, NT, K, A0p); STG(Hs, 1, 0, NT, K, A0p);
    STG(Hs, 2, 0, NT, K, A0p); STG(Hs, 3, 0, NT, K, A0p);
    STG(Ws, 0, 0, NT, K, B0p); STG(Ws, 1, 0, NT, K, B0p);
    STG(Hs, 0, 1, NT, K, A1p); STG(Hs, 1, 1, NT, K, A1p);
    STG(Hs, 2, 1, NT, K, A1p); STG(Hs, 3, 1, NT, K, A1p);
    STG(Ws, 0, 1, NT, K, B1p); STG(Ws, 1, 1, NT, K, B1p);
    WAITV(6);
    BAR();

    for (int t = 0; t < NT; t += 2) {
        DN_TILE(A0p, B0p, t)
        DN_TILE(A1p, B1p, t + 1)
    }
    WAITL(0); WAITV(0);

    #pragma unroll
    for (int m = 0; m < 4; ++m) {
        #pragma unroll
        for (int n = 0; n < 4; ++n) {
            const int row0 = brow + wr * 64 + m * 16 + kq * 4;
            const int col  = bcol + wc * 64 + n * 16 + fr;
            #pragma unroll
            for (int j = 0; j < 4; ++j) {
                Y[(size_t)(row0 + j) * 1024 + col] = acc[m][n][j];
            }
        }
    }
}

// ---------------------------------------------------------------------------
extern "C" void kernel_launch(void* const* d_in, const int* in_sizes, int n_in,
                              void* d_out, int out_size, void* d_ws, size_t ws_size,
                              hipStream_t stream) {
    const float* x  = (const float*)d_in[0];
    const float* wg = (const float*)d_in[1];
    const float* wu = (const float*)d_in[2];
    const float* wd = (const float*)d_in[3];
    float* y = (float*)d_out;

    const size_t M = 8192, H = 1024, I = 4096;

    __bf16* Xb  = (__bf16*)d_ws;
    __bf16* Wgb = Xb + M * H;
    __bf16* Wub = Wgb + I * H;
    __bf16* Wdb = Wub + I * H;
    __bf16* Hm  = Wdb + H * I;
    // needed: (M*H + 3*I*H + M*I)*2 bytes = 104 MiB

    cvt_all<<<2048, 256, 0, stream>>>(x, wg, wu, wd, Xb, Wgb, Wub, Wdb);

    ffn_gateup<<<dim3(I / 128, M / 256), 512, 0, stream>>>(Xb, Wgb, Wub, Hm);
    ffn_down  <<<dim3(H / 128, M / 256), 512, 0, stream>>>(Hm, Wdb, y);
}